// Round 8
// baseline (263.382 us; speedup 1.0000x reference)
//
#include <hip/hip_runtime.h>

#define TT 128

// LIF constants
#define DECAY_U 0.75f
#define DECAY_V 0.96875f
#define THETA   5120.0f
#define POOLW   88.0f

__device__ __forceinline__ void lif_step(float xt, float& u, float& v, int& refc, float& s) {
    u = __fadd_rn(__fmul_rn(u, DECAY_U), __fmul_rn(xt, 64.0f));
    float vn = __fadd_rn(__fmul_rn(v, DECAY_V), u);
    v = refc ? 0.0f : vn;
    s = (v >= THETA) ? 1.0f : 0.0f;
    if (s > 0.f) { refc = 1; v = 0.f; }
    else         { refc = refc > 0 ? refc - 1 : 0; }
}

// Serial LIF over an LDS column: col[t*stride], t=0..127.
__device__ __forceinline__ void lif_seq_lds(float* col, int stride) {
    float u = 0.f, v = 0.f;
    int refc = 0;
    #pragma unroll 16
    for (int t = 0; t < TT; ++t) {
        float s;
        lif_step(col[t * stride], u, v, refc, s);
        col[t * stride] = s;
    }
}

// ---------------- Weight transpose: [oc][ck] -> [ck][oc] (oc contiguous) ----------
__global__ void wtrans_k(const float* __restrict__ w1, const float* __restrict__ w2,
                         float* __restrict__ wTg1, float* __restrict__ wTg2) {
    int i = blockIdx.x * 256 + threadIdx.x;
    if (i < 800) {
        int oc = i & 15, ck = i >> 4;          // ck = c*25 + tap
        wTg1[ck*16 + oc] = w1[oc*50 + ck];
    }
    if (i < 4608) {
        int oc = i & 31, ck = i >> 5;          // ck = c*9 + tap
        wTg2[ck*32 + oc] = w2[oc*144 + ck];
    }
}

// ---------------- L1: sum_pool(x,4)*88 + LIF ----------------
__global__ void pool1_lif_k(const float* __restrict__ x, float* __restrict__ s1) {
    __shared__ float sb[TT][3];
    int t = threadIdx.x & 127, pos = threadIdx.x >> 7;
    int n = blockIdx.x * 2 + pos;
    int px = n & 31, py = (n >> 5) & 31, c = (n >> 10) & 1, b = n >> 11;
    const float* base = x + (size_t)((((b*2 + c)*128 + py*4)*128) + px*4) * 128 + t;
    float s = 0.f;
    #pragma unroll
    for (int dy = 0; dy < 4; ++dy)
        #pragma unroll
        for (int dx = 0; dx < 4; ++dx)
            s += base[(dy*128 + dx) * 128];
    sb[t][pos] = s * POOLW;
    __syncthreads();
    if (threadIdx.x < 2) lif_seq_lds(&sb[0][threadIdx.x], 3);
    __syncthreads();
    s1[(size_t)n * TT + t] = sb[t][pos];
}

// ---------------- pack s1 (2 c bits) -> pk1 [8][32][32][128] uint8 ----------------
__global__ void pack1_k(const float* __restrict__ s1, unsigned char* __restrict__ pk1) {
    int id = blockIdx.x * 256 + threadIdx.x;     // 1,048,576
    int t = id & 127;
    int pos = id >> 7;                            // b*1024 + py*32+px
    int b = pos >> 10, rem = pos & 1023;
    const float* p0 = s1 + (size_t)(b*2) * 131072 + rem * 128 + t;
    unsigned int v = (p0[0] > 0.5f ? 1u : 0u) | (p0[131072] > 0.5f ? 2u : 0u);
    pk1[id] = (unsigned char)v;
}

// ---------------- pack s3 (16 c bits) -> pk3 [8][16][16][128] uint16 ----------------
__global__ void pack2_k(const float* __restrict__ s3, unsigned short* __restrict__ pk3) {
    int id = blockIdx.x * 256 + threadIdx.x;     // 262,144
    int t = id & 127;
    int pos = id >> 7;                            // b*256 + py*16+px
    int b = pos >> 8, rem = pos & 255;
    const float* p0 = s3 + (size_t)(b*16) * 32768 + rem * 128 + t;
    unsigned int v = 0;
    #pragma unroll
    for (int c = 0; c < 16; ++c)
        v |= (p0[(size_t)c * 32768] > 0.5f ? 1u : 0u) << c;
    pk3[id] = (unsigned short)v;
}

// ---------------- L2: conv1 5x5 SAME 2->16 (delayed, packed) + LIF ----------------
// thread = (ocg 0..1 [8 oc], pos 0..3, t4 0..31 [4 t]); weights reused 4x per fetch.
__global__ __launch_bounds__(256) void conv1_lif_k(const unsigned char* __restrict__ pk1,
                                                   const float* __restrict__ wTg1,
                                                   float* __restrict__ s2) {
    __shared__ float sb[TT][65];
    int tid = threadIdx.x;
    int t4  = tid & 31;
    int pos = (tid >> 5) & 3;
    int ocg = tid >> 7;                 // wave-uniform
    int n = blockIdx.x * 4 + pos;
    int px = n & 31, py = (n >> 5) & 31, b = n >> 10;
    const unsigned char* pp = pk1 + (size_t)b * 131072;

    float acc[4][8];
    #pragma unroll
    for (int i = 0; i < 4; ++i)
        #pragma unroll
        for (int k = 0; k < 8; ++k) acc[i][k] = 0.f;

    #pragma unroll
    for (int ky = 0; ky < 5; ++ky) {
        int iy = py + ky - 2;
        unsigned int row[5][4];
        #pragma unroll
        for (int kx = 0; kx < 5; ++kx) {
            int ix = px + kx - 2;
            bool vs = ((unsigned)iy < 32u) && ((unsigned)ix < 32u);
            int iyc = vs ? iy : 0, ixc = vs ? ix : 0;
            const unsigned char* q = pp + (iyc*32 + ixc) * 128;
            #pragma unroll
            for (int i = 0; i < 4; ++i) {
                int t = t4*4 + i;
                bool v = vs && (t > 0);
                unsigned int w = q[v ? t-1 : 0];
                row[kx][i] = v ? w : 0u;
            }
        }
        #pragma unroll
        for (int kx = 0; kx < 5; ++kx) {
            const float4* wv0 = (const float4*)&wTg1[(ky*5 + kx) * 16 + ocg*8];
            const float4* wv1 = (const float4*)&wTg1[(25 + ky*5 + kx) * 16 + ocg*8];
            float4 a0 = wv0[0], a1 = wv0[1];
            float4 c0 = wv1[0], c1 = wv1[1];
            #pragma unroll
            for (int i = 0; i < 4; ++i) {
                float x0 = (float)(row[kx][i] & 1u);
                float x1 = (float)((row[kx][i] >> 1) & 1u);
                acc[i][0] = fmaf(a0.x, x0, acc[i][0]);
                acc[i][1] = fmaf(a0.y, x0, acc[i][1]);
                acc[i][2] = fmaf(a0.z, x0, acc[i][2]);
                acc[i][3] = fmaf(a0.w, x0, acc[i][3]);
                acc[i][4] = fmaf(a1.x, x0, acc[i][4]);
                acc[i][5] = fmaf(a1.y, x0, acc[i][5]);
                acc[i][6] = fmaf(a1.z, x0, acc[i][6]);
                acc[i][7] = fmaf(a1.w, x0, acc[i][7]);
                acc[i][0] = fmaf(c0.x, x1, acc[i][0]);
                acc[i][1] = fmaf(c0.y, x1, acc[i][1]);
                acc[i][2] = fmaf(c0.z, x1, acc[i][2]);
                acc[i][3] = fmaf(c0.w, x1, acc[i][3]);
                acc[i][4] = fmaf(c1.x, x1, acc[i][4]);
                acc[i][5] = fmaf(c1.y, x1, acc[i][5]);
                acc[i][6] = fmaf(c1.z, x1, acc[i][6]);
                acc[i][7] = fmaf(c1.w, x1, acc[i][7]);
            }
        }
    }
    // stage: neuron nl = oc*4 + pos, oc = ocg*8 + k
    #pragma unroll
    for (int i = 0; i < 4; ++i) {
        int t = t4*4 + i;
        #pragma unroll
        for (int k = 0; k < 8; ++k)
            sb[t][(ocg*8 + k)*4 + pos] = acc[i][k];
    }
    __syncthreads();
    if (tid < 64) lif_seq_lds(&sb[0][tid], 65);
    __syncthreads();
    int t = tid & 127, pq = tid >> 7;
    #pragma unroll
    for (int j = 0; j < 2; ++j) {
        int pos2 = pq*2 + j;
        int n2 = blockIdx.x * 4 + pos2;
        int px2 = n2 & 31, py2 = (n2 >> 5) & 31;
        size_t obase = (((size_t)(b*16) * 32 + py2) * 32 + px2) * 128 + t;
        #pragma unroll
        for (int oc = 0; oc < 16; ++oc)
            s2[obase + (size_t)oc * 131072] = sb[t][oc*4 + pos2];
    }
}

// ---------------- L3: sum_pool(s2,2)*88 (delayed) + LIF ----------------
__global__ void pool2_lif_k(const float* __restrict__ s2, float* __restrict__ s3) {
    __shared__ float sb[TT][3];
    int t = threadIdx.x & 127, pos = threadIdx.x >> 7;
    int n = blockIdx.x * 2 + pos;
    int px = n & 15, py = (n >> 4) & 15, c = (n >> 8) & 15, b = n >> 12;
    float acc = 0.f;
    if (t > 0) {
        const float* ip = s2 + (size_t)(((b*16 + c)*32 + py*2)*32 + px*2) * 128 + (t - 1);
        acc = (ip[0] + ip[128] + ip[32*128] + ip[33*128]) * POOLW;
    }
    sb[t][pos] = acc;
    __syncthreads();
    if (threadIdx.x < 2) lif_seq_lds(&sb[0][threadIdx.x], 3);
    __syncthreads();
    s3[(size_t)n * TT + t] = sb[t][pos];
}

// ---------------- L4: conv2 3x3 SAME 16->32 (delayed, packed) + LIF ----------------
// thread = (ocg 0..3 [8 oc], pos 0..1, t4 0..31 [4 t]); weights reused 4x per fetch.
__global__ __launch_bounds__(256) void conv2_lif_k(const unsigned short* __restrict__ pk3,
                                                   const float* __restrict__ wTg2,
                                                   float* __restrict__ s4) {
    __shared__ float sb[TT][65];
    int tid = threadIdx.x;
    int t4  = tid & 31;
    int pos = (tid >> 5) & 1;
    int ocg = tid >> 6;                 // 0..3, wave-uniform
    int n = blockIdx.x * 2 + pos;
    int px = n & 15, py = (n >> 4) & 15, b = n >> 8;
    const unsigned short* pp = pk3 + (size_t)b * 32768;

    // all 9 taps x 4 t packed words upfront
    unsigned int pkv[9][4];
    #pragma unroll
    for (int ky = 0; ky < 3; ++ky) {
        int iy = py + ky - 1;
        #pragma unroll
        for (int kx = 0; kx < 3; ++kx) {
            int ix = px + kx - 1;
            bool vs = ((unsigned)iy < 16u) && ((unsigned)ix < 16u);
            int iyc = vs ? iy : 0, ixc = vs ? ix : 0;
            const unsigned short* q = pp + (iyc*16 + ixc) * 128;
            #pragma unroll
            for (int i = 0; i < 4; ++i) {
                int t = t4*4 + i;
                bool v = vs && (t > 0);
                unsigned int w = q[v ? t-1 : 0];
                pkv[ky*3 + kx][i] = v ? w : 0u;
            }
        }
    }

    float acc[4][8];
    #pragma unroll
    for (int i = 0; i < 4; ++i)
        #pragma unroll
        for (int k = 0; k < 8; ++k) acc[i][k] = 0.f;

    #pragma unroll
    for (int c = 0; c < 16; ++c) {
        #pragma unroll
        for (int tap = 0; tap < 9; ++tap) {
            const float4* wv = (const float4*)&wTg2[(c*9 + tap) * 32 + ocg*8];
            float4 w0 = wv[0], w1 = wv[1];
            #pragma unroll
            for (int i = 0; i < 4; ++i) {
                float xc = (float)((pkv[tap][i] >> c) & 1u);
                acc[i][0] = fmaf(w0.x, xc, acc[i][0]);
                acc[i][1] = fmaf(w0.y, xc, acc[i][1]);
                acc[i][2] = fmaf(w0.z, xc, acc[i][2]);
                acc[i][3] = fmaf(w0.w, xc, acc[i][3]);
                acc[i][4] = fmaf(w1.x, xc, acc[i][4]);
                acc[i][5] = fmaf(w1.y, xc, acc[i][5]);
                acc[i][6] = fmaf(w1.z, xc, acc[i][6]);
                acc[i][7] = fmaf(w1.w, xc, acc[i][7]);
            }
        }
    }
    // stage: neuron nl = oc*2 + pos, oc = ocg*8 + k
    #pragma unroll
    for (int i = 0; i < 4; ++i) {
        int t = t4*4 + i;
        #pragma unroll
        for (int k = 0; k < 8; ++k)
            sb[t][(ocg*8 + k)*2 + pos] = acc[i][k];
    }
    __syncthreads();
    if (tid < 64) lif_seq_lds(&sb[0][tid], 65);
    __syncthreads();
    int t = tid & 127, p2 = tid >> 7;
    int n2 = blockIdx.x * 2 + p2;
    int px2 = n2 & 15, py2 = (n2 >> 4) & 15;
    size_t obase = (((size_t)(b*32) * 16 + py2) * 16 + px2) * 128 + t;
    #pragma unroll
    for (int oc = 0; oc < 32; ++oc)
        s4[obase + (size_t)oc * 32768] = sb[t][oc*2 + p2];
}

// ---------------- L5: sum_pool(s4,2)*88 (delayed) + LIF ----------------
__global__ void pool3_lif_k(const float* __restrict__ s4, float* __restrict__ s5) {
    __shared__ float sb[TT][3];
    int t = threadIdx.x & 127, pos = threadIdx.x >> 7;
    int n = blockIdx.x * 2 + pos;
    int px = n & 7, py = (n >> 3) & 7, c = (n >> 6) & 31, b = n >> 11;
    float acc = 0.f;
    if (t > 0) {
        const float* ip = s4 + (size_t)(((b*32 + c)*16 + py*2)*16 + px*2) * 128 + (t - 1);
        acc = (ip[0] + ip[128] + ip[16*128] + ip[17*128]) * POOLW;
    }
    sb[t][pos] = acc;
    __syncthreads();
    if (threadIdx.x < 2) lif_seq_lds(&sb[0][threadIdx.x], 3);
    __syncthreads();
    s5[(size_t)n * TT + t] = sb[t][pos];
}

// ---------------- L6: fc1 tiled K-split GEMM ----------------
__global__ __launch_bounds__(256) void fc1_gemm_k(const float* __restrict__ s5,
                                                  const float* __restrict__ wf1,
                                                  float* __restrict__ part) {
    __shared__ float WT[64][68];
    __shared__ float ST[64][68];
    int bid = blockIdx.x;
    int kc = bid & 7;
    int ot = (bid >> 3) & 7;
    int tt = (bid >> 6) & 1;
    int b  = bid >> 7;
    int tid = threadIdx.x;
    int oo = tid >> 4;
    int to = tid & 15;

    const float* wbase = wf1 + (size_t)(ot*64) * 2048 + kc*256;
    const float* sbase = s5 + (size_t)b * 262144 + (size_t)(kc*256) * 128;

    float acc[4][4];
    #pragma unroll
    for (int i = 0; i < 4; ++i)
        #pragma unroll
        for (int j = 0; j < 4; ++j) acc[i][j] = 0.f;

    for (int ks = 0; ks < 4; ++ks) {
        __syncthreads();
        #pragma unroll
        for (int i = 0; i < 16; ++i) {
            int e = tid + 256*i;
            int o = e >> 6, f = e & 63;
            WT[f][o] = wbase[(size_t)o * 2048 + ks*64 + f];
        }
        #pragma unroll
        for (int i = 0; i < 16; ++i) {
            int e = tid + 256*i;
            int f = e >> 6, tl = e & 63;
            int tsrc = tt*64 + tl - 1;
            ST[f][tl] = (tsrc < 0) ? 0.f : sbase[(size_t)f * 128 + ks*64*128 + tsrc];
        }
        __syncthreads();
        #pragma unroll 4
        for (int k = 0; k < 64; ++k) {
            float4 a = *(const float4*)&WT[k][oo*4];
            float4 s = *(const float4*)&ST[k][to*4];
            acc[0][0] = fmaf(a.x, s.x, acc[0][0]);
            acc[0][1] = fmaf(a.x, s.y, acc[0][1]);
            acc[0][2] = fmaf(a.x, s.z, acc[0][2]);
            acc[0][3] = fmaf(a.x, s.w, acc[0][3]);
            acc[1][0] = fmaf(a.y, s.x, acc[1][0]);
            acc[1][1] = fmaf(a.y, s.y, acc[1][1]);
            acc[1][2] = fmaf(a.y, s.z, acc[1][2]);
            acc[1][3] = fmaf(a.y, s.w, acc[1][3]);
            acc[2][0] = fmaf(a.z, s.x, acc[2][0]);
            acc[2][1] = fmaf(a.z, s.y, acc[2][1]);
            acc[2][2] = fmaf(a.z, s.z, acc[2][2]);
            acc[2][3] = fmaf(a.z, s.w, acc[2][3]);
            acc[3][0] = fmaf(a.w, s.x, acc[3][0]);
            acc[3][1] = fmaf(a.w, s.y, acc[3][1]);
            acc[3][2] = fmaf(a.w, s.z, acc[3][2]);
            acc[3][3] = fmaf(a.w, s.w, acc[3][3]);
        }
    }
    float* pb = part + (size_t)kc * 524288 + (size_t)b * 65536
              + (size_t)(ot*64 + oo*4) * 128 + tt*64 + to*4;
    #pragma unroll
    for (int i = 0; i < 4; ++i)
        #pragma unroll
        for (int j = 0; j < 4; ++j)
            pb[(size_t)i * 128 + j] = acc[i][j];
}

// ---------------- L6b: sum 8 K-chunks (fixed order) + LIF -> s6 ----------------
__global__ void fc1_reduce_lif_k(const float* __restrict__ part, float* __restrict__ s6) {
    __shared__ float sb[TT][3];
    int t = threadIdx.x & 127, pos = threadIdx.x >> 7;
    int n = blockIdx.x * 2 + pos;
    float s = 0.f;
    #pragma unroll
    for (int kc = 0; kc < 8; ++kc)
        s += part[(size_t)kc * 524288 + (size_t)n * 128 + t];
    sb[t][pos] = s;
    __syncthreads();
    if (threadIdx.x < 2) lif_seq_lds(&sb[0][threadIdx.x], 3);
    __syncthreads();
    s6[(size_t)n * TT + t] = sb[t][pos];
}

// ---------------- L7: fc2 512->11 (delayed) + LIF + final shift -> out ----------
__global__ void fc2_lif_k(const float* __restrict__ s6, const float* __restrict__ wf2,
                          float* __restrict__ out) {
    __shared__ float sb[TT];
    int t = threadIdx.x;
    int o = blockIdx.x % 11, b = blockIdx.x / 11;
    float acc = 0.f;
    if (t > 0) {
        const float* sp = s6 + (size_t)b * 65536 + (t - 1);
        const float* wp = wf2 + o * 512;
        for (int f = 0; f < 512; f += 4) {
            float4 w = *(const float4*)&wp[f];
            acc = fmaf(w.x, sp[(size_t)f * 128], acc);
            acc = fmaf(w.y, sp[(size_t)(f+1) * 128], acc);
            acc = fmaf(w.z, sp[(size_t)(f+2) * 128], acc);
            acc = fmaf(w.w, sp[(size_t)(f+3) * 128], acc);
        }
    }
    sb[t] = acc;
    __syncthreads();
    if (t == 0) lif_seq_lds(sb, 1);
    __syncthreads();
    float* q = out + (size_t)(b*11 + o) * TT;
    if (t == 0) q[0] = 0.f;
    if (t < TT - 1) q[t + 1] = sb[t];
}

extern "C" void kernel_launch(void* const* d_in, const int* in_sizes, int n_in,
                              void* d_out, int out_size, void* d_ws, size_t ws_size,
                              hipStream_t stream) {
    const float* x   = (const float*)d_in[0];
    const float* w1  = (const float*)d_in[1];
    const float* w2  = (const float*)d_in[2];
    const float* wf1 = (const float*)d_in[3];
    const float* wf2 = (const float*)d_in[4];
    float* out = (float*)d_out;

    float* ws = (float*)d_ws;
    float* A    = ws;                        // 4,194,304 floats (s1/s3/s5)
    float* B    = ws + 4194304;              // 16,777,216 floats (s2; later s6)
    float* PART = B + 1048576;               // 4,194,304 floats
    float* D4   = ws + 4194304 + 16777216;   // 8,388,608 floats (s4)
    float* WT1  = D4 + 8388608;              // 800 floats
    float* WT2  = WT1 + 800;                 // 4608 floats
    unsigned char*  PK1 = (unsigned char*)(WT2 + 4608);     // 1,048,576 B
    unsigned short* PK3 = (unsigned short*)(PK1 + 1048576); // 262,144 x 2B

    // W transpose (oc contiguous) for the SGPR weight path
    wtrans_k<<<dim3(18), 256, 0, stream>>>(w1, w2, WT1, WT2);
    // L1: pool1+LIF   (A = s1)
    pool1_lif_k<<<dim3(8192), 256, 0, stream>>>(x, A);
    // pack s1 -> PK1
    pack1_k<<<dim3(4096), 256, 0, stream>>>(A, PK1);
    // L2: conv1+LIF   (B = s2)  [4 pos/block]
    conv1_lif_k<<<dim3(2048), 256, 0, stream>>>(PK1, WT1, B);
    // L3: pool2+LIF   (A = s3)
    pool2_lif_k<<<dim3(16384), 256, 0, stream>>>(B, A);
    // pack s3 -> PK3
    pack2_k<<<dim3(1024), 256, 0, stream>>>(A, PK3);
    // L4: conv2+LIF   (D4 = s4)
    conv2_lif_k<<<dim3(1024), 256, 0, stream>>>(PK3, WT2, D4);
    // L5: pool3+LIF   (A = s5)
    pool3_lif_k<<<dim3(8192), 256, 0, stream>>>(D4, A);
    // L6: fc1 GEMM -> PART; reduce+LIF -> B (s6)
    fc1_gemm_k      <<<dim3(1024), 256, 0, stream>>>(A, wf1, PART);
    fc1_reduce_lif_k<<<dim3(2048), 256, 0, stream>>>(PART, B);
    // L7: fc2+LIF+shift -> d_out
    fc2_lif_k<<<dim3(88), 128, 0, stream>>>(B, wf2, out);
}